// Round 2
// baseline (438.817 us; speedup 1.0000x reference)
//
#include <hip/hip_runtime.h>
#include <math.h>

#define HD 4096  // H == D == 4096

__device__ __forceinline__ float dot4(float4 a, float4 b) {
    return a.x * b.x + a.y * b.y + a.z * b.z + a.w * b.w;
}

// ---------------------------------------------------------------------------
// Kernel 1: fused 6-way GEMV + gate math.
// One wave (64 lanes) per output row; 4 waves (256 threads) per block.
// The 6 matrices are walked in ONE interleaved k-loop with 6 independent
// accumulators -> 6 independent global load streams per k-step (deep MLP),
// instead of 6 sequential row-dots each with a serial dependence chain.
// x (16 KB) is read straight from global; it is L1-resident after the first
// touch, and skipping LDS removes the __syncthreads + lgkmcnt coupling.
// ---------------------------------------------------------------------------
__global__ __launch_bounds__(256) void k_gemv6(
    const float* __restrict__ x,
    const float* __restrict__ n_prev, const float* __restrict__ m_prev,
    const float* __restrict__ Wq, const float* __restrict__ bq,
    const float* __restrict__ Wk, const float* __restrict__ bk,
    const float* __restrict__ Wv, const float* __restrict__ bv,
    const float* __restrict__ Wi, const float* __restrict__ bi,
    const float* __restrict__ Wf, const float* __restrict__ bf,
    const float* __restrict__ Wo, const float* __restrict__ bo,
    float* __restrict__ ws_q, float* __restrict__ ws_v,
    float* __restrict__ ws_o, float* __restrict__ ws_fg,
    float* __restrict__ ws_ik,
    float* __restrict__ out_n, float* __restrict__ out_m)
{
    const int tid  = threadIdx.x;
    const int wave = tid >> 6;
    const int lane = tid & 63;
    const int row  = blockIdx.x * 4 + wave;

    const size_t roff = (size_t)row * HD;
    const float4* q4 = (const float4*)(Wq + roff);
    const float4* k4 = (const float4*)(Wk + roff);
    const float4* v4 = (const float4*)(Wv + roff);
    const float4* i4 = (const float4*)(Wi + roff);
    const float4* f4 = (const float4*)(Wf + roff);
    const float4* o4 = (const float4*)(Wo + roff);
    const float4* x4 = (const float4*)x;

    float aq = 0.f, ak = 0.f, av = 0.f, ai = 0.f, af = 0.f, ao = 0.f;
#pragma unroll 4
    for (int t = 0; t < 16; ++t) {
        const int idx = t * 64 + lane;
        float4 xv = x4[idx];
        float4 wq = q4[idx];
        float4 wk = k4[idx];
        float4 wv = v4[idx];
        float4 wi = i4[idx];
        float4 wf = f4[idx];
        float4 wo = o4[idx];
        aq += dot4(wq, xv);
        ak += dot4(wk, xv);
        av += dot4(wv, xv);
        ai += dot4(wi, xv);
        af += dot4(wf, xv);
        ao += dot4(wo, xv);
    }
#pragma unroll
    for (int off = 32; off > 0; off >>= 1) {
        aq += __shfl_xor(aq, off, 64);
        ak += __shfl_xor(ak, off, 64);
        av += __shfl_xor(av, off, 64);
        ai += __shfl_xor(ai, off, 64);
        af += __shfl_xor(af, off, 64);
        ao += __shfl_xor(ao, off, 64);
    }

    if (lane == 0) {
        float q  = aq + bq[row];
        float k  = (ak + bk[row]) * (1.0f / 64.0f);  // 1/sqrt(4096)
        float v  = av + bv[row];
        float it = ai + bi[row];
        float ft = af + bf[row];
        float o  = 1.0f / (1.0f + expf(-(ao + bo[row])));
        float mp = m_prev[row];
        float mt = fmaxf(ft + mp, it);
        float ig = expf(it - mt);
        float fg = expf(ft + mp - mt);
        float nt = fg * n_prev[row] + ig * k;
        ws_q[row]  = q;
        ws_v[row]  = v;
        ws_o[row]  = o;
        ws_fg[row] = fg;
        ws_ik[row] = ig * k;
        out_n[row] = nt;
        out_m[row] = mt;
    }
}

// ---------------------------------------------------------------------------
// Kernel 2: denom_raw = n_t . q  (max/abs applied by consumer).  One block,
// 1024 threads: each thread owns exactly one float4 of n and q.
// ---------------------------------------------------------------------------
__global__ __launch_bounds__(1024) void k_denom(
    const float* __restrict__ out_n, const float* __restrict__ ws_q,
    float* __restrict__ denom)
{
    const int tid = threadIdx.x;
    const float4* n4 = (const float4*)out_n;
    const float4* q4 = (const float4*)ws_q;
    float acc = dot4(n4[tid], q4[tid]);
#pragma unroll
    for (int off = 32; off > 0; off >>= 1) acc += __shfl_xor(acc, off, 64);
    __shared__ float red[16];
    if ((tid & 63) == 0) red[tid >> 6] = acc;
    __syncthreads();
    if (tid == 0) {
        float s = 0.f;
#pragma unroll
        for (int w = 0; w < 16; ++w) s += red[w];
        denom[0] = fmaxf(fabsf(s), 1.0f);
    }
}

// ---------------------------------------------------------------------------
// Kernel 3: c_t[r][c] = f_g[c]*c_prev[r][c] + ik[c]*v[r]  (broadcast over
// LAST axis), fused with h_t[r] = o[r] * (c_t[r,:].q) / denom.
// TWO rows per block: the column vectors (fg/ik/q) are loaded once per idx
// and feed two independent c_prev streams -> 2x global MLP per thread.
// ---------------------------------------------------------------------------
__global__ __launch_bounds__(256) void k_ct(
    const float* __restrict__ c_prev,
    const float* __restrict__ ws_q, const float* __restrict__ ws_v,
    const float* __restrict__ ws_o, const float* __restrict__ ws_fg,
    const float* __restrict__ ws_ik, const float* __restrict__ denom,
    float* __restrict__ out_h, float* __restrict__ out_c)
{
    const int r0  = blockIdx.x * 2;
    const int r1  = r0 + 1;
    const int tid = threadIdx.x;
    const float v0 = ws_v[r0];
    const float v1 = ws_v[r1];

    const float4* cp0 = (const float4*)(c_prev + (size_t)r0 * HD);
    const float4* cp1 = (const float4*)(c_prev + (size_t)r1 * HD);
    float4*       ct0p = (float4*)(out_c + (size_t)r0 * HD);
    float4*       ct1p = (float4*)(out_c + (size_t)r1 * HD);
    const float4* fg4 = (const float4*)ws_fg;
    const float4* ik4 = (const float4*)ws_ik;
    const float4* q4  = (const float4*)ws_q;

    float acc0 = 0.f, acc1 = 0.f;
#pragma unroll
    for (int t = 0; t < 4; ++t) {
        const int idx = t * 256 + tid;
        float4 f  = fg4[idx];
        float4 ik = ik4[idx];
        float4 qq = q4[idx];
        float4 c0 = cp0[idx];
        float4 c1 = cp1[idx];
        float4 a, b;
        a.x = f.x * c0.x + ik.x * v0;  b.x = f.x * c1.x + ik.x * v1;
        a.y = f.y * c0.y + ik.y * v0;  b.y = f.y * c1.y + ik.y * v1;
        a.z = f.z * c0.z + ik.z * v0;  b.z = f.z * c1.z + ik.z * v1;
        a.w = f.w * c0.w + ik.w * v0;  b.w = f.w * c1.w + ik.w * v1;
        ct0p[idx] = a;
        ct1p[idx] = b;
        acc0 += dot4(a, qq);
        acc1 += dot4(b, qq);
    }
#pragma unroll
    for (int off = 32; off > 0; off >>= 1) {
        acc0 += __shfl_xor(acc0, off, 64);
        acc1 += __shfl_xor(acc1, off, 64);
    }
    __shared__ float red0[4], red1[4];
    if ((tid & 63) == 0) { red0[tid >> 6] = acc0; red1[tid >> 6] = acc1; }
    __syncthreads();
    if (tid == 0) {
        float s0 = red0[0] + red0[1] + red0[2] + red0[3];
        float s1 = red1[0] + red1[1] + red1[2] + red1[3];
        float inv = 1.0f / denom[0];
        out_h[r0] = ws_o[r0] * s0 * inv;
        out_h[r1] = ws_o[r1] * s1 * inv;
    }
}

// ---------------------------------------------------------------------------
extern "C" void kernel_launch(void* const* d_in, const int* in_sizes, int n_in,
                              void* d_out, int out_size, void* d_ws, size_t ws_size,
                              hipStream_t stream) {
    const float* x      = (const float*)d_in[0];
    /* d_in[1] = h_prev: unused by the reference */
    const float* c_prev = (const float*)d_in[2];
    const float* n_prev = (const float*)d_in[3];
    const float* m_prev = (const float*)d_in[4];
    const float* Wq = (const float*)d_in[5];  const float* bq = (const float*)d_in[6];
    const float* Wk = (const float*)d_in[7];  const float* bk = (const float*)d_in[8];
    const float* Wv = (const float*)d_in[9];  const float* bv = (const float*)d_in[10];
    const float* Wi = (const float*)d_in[11]; const float* bi = (const float*)d_in[12];
    const float* Wf = (const float*)d_in[13]; const float* bf = (const float*)d_in[14];
    const float* Wo = (const float*)d_in[15]; const float* bo = (const float*)d_in[16];

    // Output layout: h_t [H], c_t [H,H], n_t [H], m_t [H] — flat concat.
    float* out   = (float*)d_out;
    float* out_h = out;
    float* out_c = out + HD;
    float* out_n = out + HD + (size_t)HD * HD;
    float* out_m = out_n + HD;

    // Workspace layout (floats): q, v, o, f_g, i_g*k, denom
    float* ws    = (float*)d_ws;
    float* ws_q  = ws;
    float* ws_v  = ws + 1 * HD;
    float* ws_o  = ws + 2 * HD;
    float* ws_fg = ws + 3 * HD;
    float* ws_ik = ws + 4 * HD;
    float* denom = ws + 5 * HD;

    k_gemv6<<<HD / 4, 256, 0, stream>>>(x, n_prev, m_prev,
                                        Wq, bq, Wk, bk, Wv, bv,
                                        Wi, bi, Wf, bf, Wo, bo,
                                        ws_q, ws_v, ws_o, ws_fg, ws_ik,
                                        out_n, out_m);
    k_denom<<<1, 1024, 0, stream>>>(out_n, ws_q, denom);
    k_ct<<<HD / 2, 256, 0, stream>>>(c_prev, ws_q, ws_v, ws_o, ws_fg, ws_ik,
                                     denom, out_h, out_c);
}